// Round 5
// baseline (325.970 us; speedup 1.0000x reference)
//
#include <hip/hip_runtime.h>
#include <cstdint>
#include <cstddef>

#define NN 30000
#define NE 480000
#define NG 128
#define DIN 128
#define DH 256
#define NC 60
#define CAP 64               // bucket capacity per node (true deg ~ Poisson(16); P(>64) ~ 1e-20)
#define P1MAX (NN * DIN / 4) // 960000: widest job in pre phase

typedef _Float16 f16x8 __attribute__((ext_vector_type(8)));
typedef _Float16 half4_t __attribute__((ext_vector_type(4)));
typedef float f32x4 __attribute__((ext_vector_type(4)));

// async global->LDS, 16B per lane (wave-uniform base + lane*16 dest required)
__device__ __forceinline__ void gload_lds16(const _Float16* g, _Float16* l) {
    __builtin_amdgcn_global_load_lds(
        (const __attribute__((address_space(1))) void*)g,
        (__attribute__((address_space(3))) void*)l, 16, 0, 0);
}

// ---------------- fused pre: bucket edges + x->fp16 + W->fp16 + zero sums ----------------
__global__ __launch_bounds__(256) void k_pre(const int* __restrict__ ei, int* __restrict__ cursor,
        int* __restrict__ csr_src,
        const float* __restrict__ x, _Float16* __restrict__ xh,
        const float* __restrict__ W1, const float* __restrict__ W2, const float* __restrict__ W3,
        _Float16* __restrict__ w1h, _Float16* __restrict__ w2h, _Float16* __restrict__ w3h,
        float* __restrict__ sums) {
    int i = blockIdx.x * 256 + threadIdx.x;
    if (i < NE) {
        int s = ei[i];        // edge_index[0]
        int d = ei[NE + i];   // edge_index[1]
        int slot = atomicAdd(&cursor[d], 1);
        if (slot < CAP) csr_src[d * CAP + slot] = s;
    }
    if (i < P1MAX) {
        float4 v = ((const float4*)x)[i];
        half4_t o;
        o[0] = (_Float16)v.x; o[1] = (_Float16)v.y;
        o[2] = (_Float16)v.z; o[3] = (_Float16)v.w;
        ((half4_t*)xh)[i] = o;
    }
    if (i < DH * DIN) w1h[i] = (_Float16)W1[i];
    if (i < DH * DH) {
        w2h[i] = (_Float16)W2[i];
        w3h[i] = (_Float16)W3[i];
    }
    if (i < NG * DH) sums[i] = 0.f;
}

// ---------------- aggregation: u[v] = sum_e w_e*hin[src_e] + hin[v]/(deg_v+1) ----------------
// XCD-sliced at 128 B granularity (round-3 retry with its 3 regression causes fixed):
//  - COLS = 64 halves = 128 B = one full L2 line per slice -> no half-line fill waste.
//    K=256: SL=4, slice s pinned to XCDs {s,s+4} by round-robin dispatch (bid%SL);
//    hot gather set = 30000 * 128 B = 3.84 MB -> fits the 4 MB per-XCD L2.
//  - r1-proven tiered loop: predicated 16-edge rounds, 2 row-gathers + 2 cnt-gathers in
//    flight per lane (round 3 had 1 -> latency-serial).
//  - metadata inline (cnt gather + rsqrt): chip-wide lane-slots identical to unsliced
//    (round-4 lesson: streams only add bytes); csr is the only duplicated stream (x SL).
// NT hints: csr loads + tout stores evict-first so the hot plane slice owns the L2.
// One wave per (node, slice); L=8 lanes/edge, G=8 edges/round; butterfly over masks
// 8/16/32 at the end. fp16 plane in/out, fp32 accumulate.
template<int K>
__global__ __launch_bounds__(256) void k_agg(const _Float16* __restrict__ hin,
        _Float16* __restrict__ tout, const int* __restrict__ cnt,
        const int* __restrict__ csr_src) {
    constexpr int SL = K / 64;     // 4 (K=256) / 2 (K=128) slices of 128 B
    int bid = blockIdx.x;
    int slice = bid % SL;          // consecutive bids -> consecutive XCDs
    int nb = bid / SL;
    int node = nb * 4 + (threadIdx.x >> 6);
    int lane = threadIdx.x & 63;
    int sub = lane >> 3;           // edge slot 0..7 within the round
    int off = lane & 7;            // 16 B chunk 0..7 within the 128 B slice
    const _Float16* gbase = hin + slice * 64 + off * 8;
    float acc[8];
    #pragma unroll
    for (int u = 0; u < 8; u++) acc[u] = 0.f;
    int deg = cnt[node];
    float dvd = rsqrtf((float)(deg + 1));
    int c = deg < CAP ? deg : CAP;
    int beg = node * CAP, end = beg + c;
    // predicated 16-edge rounds: typical deg~16 node = 1 round
    for (int e = beg; e < end; e += 16) {
        int s[2]; float w[2]; f16x8 r[2];
        #pragma unroll
        for (int j = 0; j < 2; j++) {
            int idx = e + j * 8 + sub;
            s[j] = (idx < end) ? __builtin_nontemporal_load(&csr_src[idx]) : node;
        }
        #pragma unroll
        for (int j = 0; j < 2; j++)
            r[j] = *(const f16x8*)(gbase + (size_t)s[j] * K);
        #pragma unroll
        for (int j = 0; j < 2; j++) {
            int idx = e + j * 8 + sub;
            w[j] = (idx < end) ? rsqrtf((float)(cnt[s[j]] + 1)) * dvd : 0.f;
        }
        #pragma unroll
        for (int j = 0; j < 2; j++)
            #pragma unroll
            for (int u = 0; u < 8; u++) acc[u] = fmaf(w[j], (float)r[j][u], acc[u]);
    }
    // self loop: weight 1/(deg+1), counted once (sub==0 lanes only)
    {
        float sws = (sub == 0) ? dvd * dvd : 0.f;
        f16x8 rs = *(const f16x8*)(gbase + (size_t)node * K);
        #pragma unroll
        for (int u = 0; u < 8; u++) acc[u] = fmaf(sws, (float)rs[u], acc[u]);
    }
    // butterfly reduce across the 8 edge slots (partners share 'off')
    #pragma unroll
    for (int u = 0; u < 8; u++) {
        float v = acc[u];
        #pragma unroll
        for (int m = 8; m < 64; m <<= 1) v += __shfl_xor(v, m, 64);
        acc[u] = v;
    }
    if (sub == 0) {
        f16x8 o;
        #pragma unroll
        for (int u = 0; u < 8; u++) o[u] = (_Float16)acc[u];
        __builtin_nontemporal_store(o, (f16x8*)(tout + (size_t)node * K + slice * 64 + off * 8));
    }
}

// ---------------- fp16 MFMA GEMM: C[M x 256] = relu(A * W^T + bias) ----------------
// BM=64 x BN=64, BK=32, 4 waves, wave tile 32x32 (2x2 of 16x16x32). Single-buffered:
// the round-2 dbuf variant (32 KB LDS) capped residency at 5 blocks/CU and regressed;
// 8 KB LDS keeps 8 blocks/CU (~8 waves/SIMD) and TLP hides the staging drain.
// Staging via global_load_lds width=16; LDS stride 32 halves UNPADDED (lane-contiguous
// dest constraint; thread t's 16B chunk lands at t*16 B).
// FUSE_POOL=true (layer 3): epilogue run-sums per graph (batch sorted) -> atomicAdd.
template<int K, bool FUSE_POOL>
__global__ __launch_bounds__(256) void k_gemm(const _Float16* __restrict__ A,
        const _Float16* __restrict__ W, const float* __restrict__ bias,
        _Float16* __restrict__ Cb, const int* __restrict__ batch,
        float* __restrict__ sums) {
    __shared__ __align__(16) _Float16 lsA[64 * 32];
    __shared__ __align__(16) _Float16 lsB[64 * 32];
    int t = threadIdx.x;
    int bm = blockIdx.x * 64;
    int bn = blockIdx.y * 64;
    int lane = t & 63, wv = t >> 6;
    int wm = (wv & 1) * 32;
    int wn = (wv >> 1) * 32;
    int lm = lane & 15, q = lane >> 4;
    int r4 = t >> 2;
    int c4 = t & 3;
    int ra = bm + r4; if (ra >= NN) ra = NN - 1;
    int rb = bn + r4;

    f32x4 acc[2][2];
    #pragma unroll
    for (int i = 0; i < 2; i++)
        #pragma unroll
        for (int j = 0; j < 2; j++) acc[i][j] = (f32x4){0.f, 0.f, 0.f, 0.f};

    for (int k0 = 0; k0 < K; k0 += 32) {
        size_t ko = (size_t)k0 + c4 * 8;
        __syncthreads();  // previous tile fully consumed before LDS overwrite
        // thread t -> LDS half-offset r4*32 + c4*8 == t*8 (lane-contiguous 16B chunks)
        gload_lds16(A + (size_t)ra * K + ko, lsA + t * 8);
        gload_lds16(W + (size_t)rb * K + ko, lsB + t * 8);
        __syncthreads();  // drains vmcnt (compiler inserts) + all lanes staged
        f16x8 bf[2];
        #pragma unroll
        for (int nt = 0; nt < 2; nt++)
            bf[nt] = *(const f16x8*)&lsB[(wn + nt * 16 + lm) * 32 + q * 8];
        #pragma unroll
        for (int mt = 0; mt < 2; mt++) {
            f16x8 af = *(const f16x8*)&lsA[(wm + mt * 16 + lm) * 32 + q * 8];
            #pragma unroll
            for (int nt = 0; nt < 2; nt++)
                acc[mt][nt] = __builtin_amdgcn_mfma_f32_16x16x32_f16(af, bf[nt], acc[mt][nt], 0, 0, 0);
        }
    }
    // epilogue: C/D layout col = lane&15, row = q*4 + r
    if constexpr (!FUSE_POOL) {
        #pragma unroll
        for (int mt = 0; mt < 2; mt++) {
            #pragma unroll
            for (int nt = 0; nt < 2; nt++) {
                int col = bn + wn + nt * 16 + lm;
                float bv = bias[col];
                #pragma unroll
                for (int r = 0; r < 4; r++) {
                    int row = bm + wm + mt * 16 + q * 4 + r;
                    if (row < NN) {
                        float v = fmaxf(acc[mt][nt][r] + bv, 0.f);
                        Cb[(size_t)row * 256 + col] = (_Float16)v;
                    }
                }
            }
        }
    } else {
        // graph ids for this lane's 8 rows (ascending; reused across nt)
        int gid[8];
        #pragma unroll
        for (int mt = 0; mt < 2; mt++)
            #pragma unroll
            for (int r = 0; r < 4; r++) {
                int row = bm + wm + mt * 16 + q * 4 + r;
                gid[mt * 4 + r] = (row < NN) ? batch[row] : -1;
            }
        #pragma unroll
        for (int nt = 0; nt < 2; nt++) {
            int col = bn + wn + nt * 16 + lm;
            float bv = bias[col];
            float runsum = 0.f;
            int curg = -1;
            #pragma unroll
            for (int mt = 0; mt < 2; mt++) {
                #pragma unroll
                for (int r = 0; r < 4; r++) {
                    int g = gid[mt * 4 + r];
                    if (g >= 0) {
                        float v = fmaxf(acc[mt][nt][r] + bv, 0.f);
                        if (g != curg) {
                            if (curg >= 0) atomicAdd(&sums[curg * DH + col], runsum);
                            curg = g;
                            runsum = 0.f;
                        }
                        runsum += v;
                    }
                }
            }
            if (curg >= 0) atomicAdd(&sums[curg * DH + col], runsum);
        }
    }
}

// ---------------- FC: out[G x 60] = (sums[g]/cnt) @ Wfc[60 x 256]^T + bfc ----------------
__global__ __launch_bounds__(64) void k_fc(const float* __restrict__ sums,
        const int* __restrict__ batch, const float* __restrict__ Wfc,
        const float* __restrict__ bfc, float* __restrict__ out) {
    __shared__ float p[DH];
    int g = blockIdx.x;
    int t = threadIdx.x;
    int lo = 0, hi = NN;
    while (lo < hi) { int mid = (lo + hi) >> 1; if (batch[mid] < g) lo = mid + 1; else hi = mid; }
    int start = lo;
    hi = NN;
    while (lo < hi) { int mid = (lo + hi) >> 1; if (batch[mid] < g + 1) lo = mid + 1; else hi = mid; }
    int cnt = lo - start;
    float inv = (cnt > 0) ? 1.f / (float)cnt : 0.f;
    for (int i = t; i < DH; i += 64) p[i] = sums[g * DH + i] * inv;
    __syncthreads();
    if (t < NC) {
        float a = bfc[t];
        for (int k = 0; k < DH; k++) a = fmaf(p[k], Wfc[t * DH + k], a);
        out[g * NC + t] = a;
    }
}

extern "C" void kernel_launch(void* const* d_in, const int* in_sizes, int n_in,
                              void* d_out, int out_size, void* d_ws, size_t ws_size,
                              hipStream_t stream) {
    const float* x     = (const float*)d_in[0];
    const int*   ei    = (const int*)d_in[1];
    const int*   batch = (const int*)d_in[2];
    const float* W1 = (const float*)d_in[3];
    const float* b1 = (const float*)d_in[4];
    const float* W2 = (const float*)d_in[5];
    const float* b2 = (const float*)d_in[6];
    const float* W3 = (const float*)d_in[7];
    const float* b3 = (const float*)d_in[8];
    const float* Wfc = (const float*)d_in[9];
    const float* bfc = (const float*)d_in[10];
    float* out = (float*)d_out;

    char* wp = (char*)d_ws;
    auto alloc = [&](size_t bytes) {
        char* q = wp;
        wp += (bytes + 511) & ~(size_t)511;
        return (void*)q;
    };
    int*   cursor  = (int*)alloc((size_t)NN * 4);               // true in-degree after pre
    int*   csr_src = (int*)alloc((size_t)NN * CAP * 4);         // bucket CSR
    float* sums    = (float*)alloc((size_t)NG * DH * 4);        // zeroed inside k_pre
    _Float16* xh   = (_Float16*)alloc((size_t)NN * DIN * 2);
    _Float16* tb   = (_Float16*)alloc((size_t)NN * DH * 2);
    _Float16* hA   = (_Float16*)alloc((size_t)NN * DH * 2);
    _Float16* hB   = (_Float16*)alloc((size_t)NN * DH * 2);
    _Float16* w1h = (_Float16*)alloc((size_t)DH * DIN * 2);
    _Float16* w2h = (_Float16*)alloc((size_t)DH * DH * 2);
    _Float16* w3h = (_Float16*)alloc((size_t)DH * DH * 2);

    // only cursor must be zero before pre's atomics (120 KB)
    hipMemsetAsync(cursor, 0, (size_t)NN * 4, stream);

    k_pre<<<(P1MAX + 255) / 256, 256, 0, stream>>>(ei, cursor, csr_src, x, xh,
                                                   W1, W2, W3, w1h, w2h, w3h, sums);

    dim3 gg((NN + 63) / 64, 4);
    // h_l = relu((A.h_{l-1}) W^T + b)  [linearity reorder]
    k_agg<128><<<(NN / 4) * 2, 256, 0, stream>>>(xh, tb, cursor, csr_src);
    k_gemm<128, false><<<gg, 256, 0, stream>>>(tb, w1h, b1, hA, nullptr, nullptr);
    k_agg<256><<<(NN / 4) * 4, 256, 0, stream>>>(hA, tb, cursor, csr_src);
    k_gemm<256, false><<<gg, 256, 0, stream>>>(tb, w2h, b2, hB, nullptr, nullptr);
    k_agg<256><<<(NN / 4) * 4, 256, 0, stream>>>(hB, tb, cursor, csr_src);
    k_gemm<256, true><<<gg, 256, 0, stream>>>(tb, w3h, b3, nullptr, batch, sums);  // + pool

    k_fc<<<NG, 64, 0, stream>>>(sums, batch, Wfc, bfc, out);
}

// Round 7
// 287.968 us; speedup vs baseline: 1.1320x; 1.1320x over previous
//
#include <hip/hip_runtime.h>
#include <cstdint>
#include <cstddef>

#define NN 30000
#define NE 480000
#define NG 128
#define DIN 128
#define DH 256
#define NC 60
#define CAP 64               // bucket capacity per node (true deg ~ Poisson(16); P(>64) ~ 1e-20)
#define P1MAX (NN * DIN / 4) // 960000: widest job in pre phase

typedef _Float16 f16x8 __attribute__((ext_vector_type(8)));
typedef _Float16 half4_t __attribute__((ext_vector_type(4)));
typedef float f32x4 __attribute__((ext_vector_type(4)));

// async global->LDS, 16B per lane (wave-uniform base + lane*16 dest required)
__device__ __forceinline__ void gload_lds16(const _Float16* g, _Float16* l) {
    __builtin_amdgcn_global_load_lds(
        (const __attribute__((address_space(1))) void*)g,
        (__attribute__((address_space(3))) void*)l, 16, 0, 0);
}

// ---------------- fused pre: bucket edges + x->fp16 + W->fp16 + zero sums ----------------
__global__ __launch_bounds__(256) void k_pre(const int* __restrict__ ei, int* __restrict__ cursor,
        int* __restrict__ csr_src,
        const float* __restrict__ x, _Float16* __restrict__ xh,
        const float* __restrict__ W1, const float* __restrict__ W2, const float* __restrict__ W3,
        _Float16* __restrict__ w1h, _Float16* __restrict__ w2h, _Float16* __restrict__ w3h,
        float* __restrict__ sums) {
    int i = blockIdx.x * 256 + threadIdx.x;
    if (i < NE) {
        int s = ei[i];        // edge_index[0]
        int d = ei[NE + i];   // edge_index[1]
        int slot = atomicAdd(&cursor[d], 1);
        if (slot < CAP) csr_src[d * CAP + slot] = s;
    }
    if (i < P1MAX) {
        float4 v = ((const float4*)x)[i];
        half4_t o;
        o[0] = (_Float16)v.x; o[1] = (_Float16)v.y;
        o[2] = (_Float16)v.z; o[3] = (_Float16)v.w;
        ((half4_t*)xh)[i] = o;
    }
    if (i < DH * DIN) w1h[i] = (_Float16)W1[i];
    if (i < DH * DH) {
        w2h[i] = (_Float16)W2[i];
        w3h[i] = (_Float16)W3[i];
    }
    if (i < NG * DH) sums[i] = 0.f;
}

// ---------------- aggregation: u[v] = sum_e w_e*hin[src_e] + hin[v]/(deg_v+1) ----------------
// Measured-best (round-2 profile: 44.3us, VALUBusy 30%) structure, restored verbatim after
// the slicing experiments (r3: x8 metadata dup; r5: x4 per-wave overhead) both regressed.
// One wave per node. 16B/lane gathers: wave splits into G = 64/(K/8) lane-groups, each
// group owns one edge of the current batch. Tiers 16/8/predicated-8: tier 16 keeps
// 8 (K=256) / 4 (K=128) row gathers in flight per lane to cover L2/LLC latency.
// Cross-group butterfly reduce at the end. fp16 plane in/out, fp32 accumulate.
template<int K>
__global__ __launch_bounds__(256) void k_agg(const _Float16* __restrict__ hin,
        _Float16* __restrict__ tout, const int* __restrict__ cnt,
        const int* __restrict__ csr_src) {
    constexpr int L = K / 8;   // lanes per row (16B chunks per row)
    constexpr int G = 64 / L;  // edges per wave round (2 for K=256, 4 for K=128)
    constexpr int B16 = 16 / G;
    constexpr int B8 = 8 / G;
    int node = blockIdx.x * 4 + (threadIdx.x >> 6);
    int lane = threadIdx.x & 63;
    int sub = lane / L;        // edge slot within the round
    int off = lane % L;        // 8-half chunk index within the row
    const _Float16* gbase = hin + off * 8;
    float acc[8];
    #pragma unroll
    for (int u = 0; u < 8; u++) acc[u] = 0.f;
    int deg = cnt[node];
    float dvd = rsqrtf((float)(deg + 1));
    int c = deg < CAP ? deg : CAP;
    int beg = node * CAP, end = beg + c;
    int e = beg;
    // tier 16: covers a whole typical (deg~16) node in one batch
    for (; e + 16 <= end; e += 16) {
        int s[B16]; float w[B16]; f16x8 r[B16];
        #pragma unroll
        for (int j = 0; j < B16; j++) s[j] = csr_src[e + j * G + sub];
        #pragma unroll
        for (int j = 0; j < B16; j++) r[j] = *(const f16x8*)(gbase + (size_t)s[j] * K);
        #pragma unroll
        for (int j = 0; j < B16; j++) w[j] = rsqrtf((float)(cnt[s[j]] + 1)) * dvd;
        #pragma unroll
        for (int j = 0; j < B16; j++)
            #pragma unroll
            for (int u = 0; u < 8; u++) acc[u] = fmaf(w[j], (float)r[j][u], acc[u]);
    }
    // predicated 8-edge rounds (<=2): idle lanes get weight 0 on a safe (self) row
    for (; e < end; e += 8) {
        int s[B8]; float w[B8]; f16x8 r[B8];
        #pragma unroll
        for (int j = 0; j < B8; j++) {
            int idx = e + j * G + sub;
            s[j] = (idx < end) ? csr_src[idx] : node;
        }
        #pragma unroll
        for (int j = 0; j < B8; j++)
            r[j] = *(const f16x8*)(gbase + (size_t)s[j] * K);
        #pragma unroll
        for (int j = 0; j < B8; j++) {
            int idx = e + j * G + sub;
            w[j] = (idx < end) ? rsqrtf((float)(cnt[s[j]] + 1)) * dvd : 0.f;
        }
        #pragma unroll
        for (int j = 0; j < B8; j++)
            #pragma unroll
            for (int u = 0; u < 8; u++) acc[u] = fmaf(w[j], (float)r[j][u], acc[u]);
    }
    // self loop: weight 1/(deg+1), counted once (only sub==0 lanes add it)
    {
        float sws = (sub == 0) ? dvd * dvd : 0.f;
        f16x8 rs = *(const f16x8*)(gbase + (size_t)node * K);
        #pragma unroll
        for (int u = 0; u < 8; u++) acc[u] = fmaf(sws, (float)rs[u], acc[u]);
    }
    // butterfly reduce across edge slots (partners share 'off' since L | mask)
    #pragma unroll
    for (int u = 0; u < 8; u++) {
        float v = acc[u];
        #pragma unroll
        for (int m = L; m < 64; m <<= 1) v += __shfl_xor(v, m, 64);
        acc[u] = v;
    }
    if (sub == 0) {
        f16x8 o;
        #pragma unroll
        for (int u = 0; u < 8; u++) o[u] = (_Float16)acc[u];
        *(f16x8*)(tout + (size_t)node * K + off * 8) = o;
    }
}

// ---------------- fp16 MFMA GEMM: C[M x 256] = relu(A * W^T + bias) ----------------
// BM=64 x BN=64, BK=64 (single change vs round 5's measured config: was BK=32).
// Halves the barrier count (K=256: 4 K-steps instead of 8) and doubles MFMA per phase
// (8/wave) -- the BK=32 loop had only 4 MFMA between barrier drains (barrier-bound).
// LDS layout is chunk-major: [chunk c=0..7][row r=0..63] x 16B, chunk c holds k-halves
// [c*8,(c+1)*8) of all rows. Wave wv stages chunks wv and 4+wv, one global_load_lds
// each: dest = base(c*1024B) + lane*16B (wave-contiguous, required); source is per-lane
// (row lane, stride K*2B -- allowed). MFMA sub-tile kk reads chunk kk*4+q: each 16-lane
// q-group reads 256 contiguous bytes -> 2 lanes/bank, conflict-free.
// LDS 16 KB/block -> 8 blocks/CU retained.
// FUSE_POOL=true (layer 3): epilogue run-sums per graph (batch sorted) -> atomicAdd.
template<int K, bool FUSE_POOL>
__global__ __launch_bounds__(256) void k_gemm(const _Float16* __restrict__ A,
        const _Float16* __restrict__ W, const float* __restrict__ bias,
        _Float16* __restrict__ Cb, const int* __restrict__ batch,
        float* __restrict__ sums) {
    __shared__ __align__(16) _Float16 lsA[8 * 64 * 8];   // 8 chunks x 64 rows x 8 halves
    __shared__ __align__(16) _Float16 lsB[8 * 64 * 8];
    int t = threadIdx.x;
    int bm = blockIdx.x * 64;
    int bn = blockIdx.y * 64;
    int lane = t & 63, wv = t >> 6;
    int wm = (wv & 1) * 32;
    int wn = (wv >> 1) * 32;
    int lm = lane & 15, q = lane >> 4;
    int ra = bm + lane; if (ra >= NN) ra = NN - 1;
    int rb = bn + lane;
    const _Float16* gA = A + (size_t)ra * K + wv * 8;
    const _Float16* gW = W + (size_t)rb * K + wv * 8;
    _Float16* dA = lsA + (wv * 64 + lane) * 8;   // chunk wv, slot lane
    _Float16* dW = lsB + (wv * 64 + lane) * 8;

    f32x4 acc[2][2];
    #pragma unroll
    for (int i = 0; i < 2; i++)
        #pragma unroll
        for (int j = 0; j < 2; j++) acc[i][j] = (f32x4){0.f, 0.f, 0.f, 0.f};

    for (int k0 = 0; k0 < K; k0 += 64) {
        __syncthreads();  // previous tile fully consumed before LDS overwrite
        gload_lds16(gA + k0,      dA);            // chunk wv   : k-halves [wv*8 .. )
        gload_lds16(gA + k0 + 32, dA + 2048);     // chunk 4+wv : k-halves [32+wv*8 .. )
        gload_lds16(gW + k0,      dW);
        gload_lds16(gW + k0 + 32, dW + 2048);
        __syncthreads();  // drains vmcnt (compiler inserts) + all lanes staged
        #pragma unroll
        for (int kk = 0; kk < 2; kk++) {
            f16x8 bf[2], af[2];
            #pragma unroll
            for (int nt = 0; nt < 2; nt++)
                bf[nt] = *(const f16x8*)&lsB[((kk * 4 + q) * 64 + (wn + nt * 16 + lm)) * 8];
            #pragma unroll
            for (int mt = 0; mt < 2; mt++)
                af[mt] = *(const f16x8*)&lsA[((kk * 4 + q) * 64 + (wm + mt * 16 + lm)) * 8];
            #pragma unroll
            for (int mt = 0; mt < 2; mt++)
                #pragma unroll
                for (int nt = 0; nt < 2; nt++)
                    acc[mt][nt] = __builtin_amdgcn_mfma_f32_16x16x32_f16(af[mt], bf[nt], acc[mt][nt], 0, 0, 0);
        }
    }
    // epilogue: C/D layout col = lane&15, row = q*4 + r
    if constexpr (!FUSE_POOL) {
        #pragma unroll
        for (int mt = 0; mt < 2; mt++) {
            #pragma unroll
            for (int nt = 0; nt < 2; nt++) {
                int col = bn + wn + nt * 16 + lm;
                float bv = bias[col];
                #pragma unroll
                for (int r = 0; r < 4; r++) {
                    int row = bm + wm + mt * 16 + q * 4 + r;
                    if (row < NN) {
                        float v = fmaxf(acc[mt][nt][r] + bv, 0.f);
                        Cb[(size_t)row * 256 + col] = (_Float16)v;
                    }
                }
            }
        }
    } else {
        // graph ids for this lane's 8 rows (ascending; reused across nt)
        int gid[8];
        #pragma unroll
        for (int mt = 0; mt < 2; mt++)
            #pragma unroll
            for (int r = 0; r < 4; r++) {
                int row = bm + wm + mt * 16 + q * 4 + r;
                gid[mt * 4 + r] = (row < NN) ? batch[row] : -1;
            }
        #pragma unroll
        for (int nt = 0; nt < 2; nt++) {
            int col = bn + wn + nt * 16 + lm;
            float bv = bias[col];
            float runsum = 0.f;
            int curg = -1;
            #pragma unroll
            for (int mt = 0; mt < 2; mt++) {
                #pragma unroll
                for (int r = 0; r < 4; r++) {
                    int g = gid[mt * 4 + r];
                    if (g >= 0) {
                        float v = fmaxf(acc[mt][nt][r] + bv, 0.f);
                        if (g != curg) {
                            if (curg >= 0) atomicAdd(&sums[curg * DH + col], runsum);
                            curg = g;
                            runsum = 0.f;
                        }
                        runsum += v;
                    }
                }
            }
            if (curg >= 0) atomicAdd(&sums[curg * DH + col], runsum);
        }
    }
}

// ---------------- FC: out[G x 60] = (sums[g]/cnt) @ Wfc[60 x 256]^T + bfc ----------------
__global__ __launch_bounds__(64) void k_fc(const float* __restrict__ sums,
        const int* __restrict__ batch, const float* __restrict__ Wfc,
        const float* __restrict__ bfc, float* __restrict__ out) {
    __shared__ float p[DH];
    int g = blockIdx.x;
    int t = threadIdx.x;
    int lo = 0, hi = NN;
    while (lo < hi) { int mid = (lo + hi) >> 1; if (batch[mid] < g) lo = mid + 1; else hi = mid; }
    int start = lo;
    hi = NN;
    while (lo < hi) { int mid = (lo + hi) >> 1; if (batch[mid] < g + 1) lo = mid + 1; else hi = mid; }
    int cnt = lo - start;
    float inv = (cnt > 0) ? 1.f / (float)cnt : 0.f;
    for (int i = t; i < DH; i += 64) p[i] = sums[g * DH + i] * inv;
    __syncthreads();
    if (t < NC) {
        float a = bfc[t];
        for (int k = 0; k < DH; k++) a = fmaf(p[k], Wfc[t * DH + k], a);
        out[g * NC + t] = a;
    }
}

extern "C" void kernel_launch(void* const* d_in, const int* in_sizes, int n_in,
                              void* d_out, int out_size, void* d_ws, size_t ws_size,
                              hipStream_t stream) {
    const float* x     = (const float*)d_in[0];
    const int*   ei    = (const int*)d_in[1];
    const int*   batch = (const int*)d_in[2];
    const float* W1 = (const float*)d_in[3];
    const float* b1 = (const float*)d_in[4];
    const float* W2 = (const float*)d_in[5];
    const float* b2 = (const float*)d_in[6];
    const float* W3 = (const float*)d_in[7];
    const float* b3 = (const float*)d_in[8];
    const float* Wfc = (const float*)d_in[9];
    const float* bfc = (const float*)d_in[10];
    float* out = (float*)d_out;

    char* wp = (char*)d_ws;
    auto alloc = [&](size_t bytes) {
        char* q = wp;
        wp += (bytes + 511) & ~(size_t)511;
        return (void*)q;
    };
    int*   cursor  = (int*)alloc((size_t)NN * 4);               // true in-degree after pre
    int*   csr_src = (int*)alloc((size_t)NN * CAP * 4);         // bucket CSR
    float* sums    = (float*)alloc((size_t)NG * DH * 4);        // zeroed inside k_pre
    _Float16* xh   = (_Float16*)alloc((size_t)NN * DIN * 2);
    _Float16* tb   = (_Float16*)alloc((size_t)NN * DH * 2);
    _Float16* hA   = (_Float16*)alloc((size_t)NN * DH * 2);
    _Float16* hB   = (_Float16*)alloc((size_t)NN * DH * 2);
    _Float16* w1h = (_Float16*)alloc((size_t)DH * DIN * 2);
    _Float16* w2h = (_Float16*)alloc((size_t)DH * DH * 2);
    _Float16* w3h = (_Float16*)alloc((size_t)DH * DH * 2);

    // only cursor must be zero before pre's atomics (120 KB)
    hipMemsetAsync(cursor, 0, (size_t)NN * 4, stream);

    k_pre<<<(P1MAX + 255) / 256, 256, 0, stream>>>(ei, cursor, csr_src, x, xh,
                                                   W1, W2, W3, w1h, w2h, w3h, sums);

    dim3 gg((NN + 63) / 64, 4);
    // h_l = relu((A.h_{l-1}) W^T + b)  [linearity reorder]
    k_agg<128><<<NN / 4, 256, 0, stream>>>(xh, tb, cursor, csr_src);
    k_gemm<128, false><<<gg, 256, 0, stream>>>(tb, w1h, b1, hA, nullptr, nullptr);
    k_agg<256><<<NN / 4, 256, 0, stream>>>(hA, tb, cursor, csr_src);
    k_gemm<256, false><<<gg, 256, 0, stream>>>(tb, w2h, b2, hB, nullptr, nullptr);
    k_agg<256><<<NN / 4, 256, 0, stream>>>(hB, tb, cursor, csr_src);
    k_gemm<256, true><<<gg, 256, 0, stream>>>(tb, w3h, b3, nullptr, batch, sums);  // + pool

    k_fc<<<NG, 64, 0, stream>>>(sums, batch, Wfc, bfc, out);
}

// Round 8
// 268.603 us; speedup vs baseline: 1.2136x; 1.0721x over previous
//
#include <hip/hip_runtime.h>
#include <cstdint>
#include <cstddef>

#define NN 30000
#define NE 480000
#define NG 128
#define DIN 128
#define DH 256
#define NC 60
#define CAP 64               // bucket capacity per node (true deg ~ Poisson(16); P(>64) ~ 1e-20)
#define P1MAX (NN * DIN / 4) // 960000: widest job in pre phase

typedef _Float16 f16x8 __attribute__((ext_vector_type(8)));
typedef _Float16 half4_t __attribute__((ext_vector_type(4)));
typedef float f32x4 __attribute__((ext_vector_type(4)));

// async global->LDS, 16B per lane (wave-uniform base + lane*16 dest required)
__device__ __forceinline__ void gload_lds16(const _Float16* g, _Float16* l) {
    __builtin_amdgcn_global_load_lds(
        (const __attribute__((address_space(1))) void*)g,
        (__attribute__((address_space(3))) void*)l, 16, 0, 0);
}

// ---------------- fused pre: bucket edges + x->fp16 + W->fp16 + zero sums ----------------
__global__ __launch_bounds__(256) void k_pre(const int* __restrict__ ei, int* __restrict__ cursor,
        int* __restrict__ csr_src,
        const float* __restrict__ x, _Float16* __restrict__ xh,
        const float* __restrict__ W1, const float* __restrict__ W2, const float* __restrict__ W3,
        _Float16* __restrict__ w1h, _Float16* __restrict__ w2h, _Float16* __restrict__ w3h,
        float* __restrict__ sums) {
    int i = blockIdx.x * 256 + threadIdx.x;
    if (i < NE) {
        int s = ei[i];        // edge_index[0]
        int d = ei[NE + i];   // edge_index[1]
        int slot = atomicAdd(&cursor[d], 1);
        if (slot < CAP) csr_src[d * CAP + slot] = s;
    }
    if (i < P1MAX) {
        float4 v = ((const float4*)x)[i];
        half4_t o;
        o[0] = (_Float16)v.x; o[1] = (_Float16)v.y;
        o[2] = (_Float16)v.z; o[3] = (_Float16)v.w;
        ((half4_t*)xh)[i] = o;
    }
    if (i < DH * DIN) w1h[i] = (_Float16)W1[i];
    if (i < DH * DH) {
        w2h[i] = (_Float16)W2[i];
        w3h[i] = (_Float16)W3[i];
    }
    if (i < NG * DH) sums[i] = 0.f;
}

// ---------------- aggregation: u[v] = sum_e w_e*hin[src_e] + hin[v]/(deg_v+1) ----------------
// Measured-best (round-2 profile: 44.3us, VALUBusy 30%) structure, kept verbatim.
// One wave per node. 16B/lane gathers: wave splits into G = 64/(K/8) lane-groups, each
// group owns one edge of the current batch. Tier 16 keeps 8 (K=256) / 4 (K=128) row
// gathers in flight per lane; predicated 8-edge rounds for the tail.
// Cross-group butterfly reduce at the end. fp16 plane in/out, fp32 accumulate.
template<int K>
__global__ __launch_bounds__(256) void k_agg(const _Float16* __restrict__ hin,
        _Float16* __restrict__ tout, const int* __restrict__ cnt,
        const int* __restrict__ csr_src) {
    constexpr int L = K / 8;   // lanes per row (16B chunks per row)
    constexpr int G = 64 / L;  // edges per wave round (2 for K=256, 4 for K=128)
    constexpr int B16 = 16 / G;
    constexpr int B8 = 8 / G;
    int node = blockIdx.x * 4 + (threadIdx.x >> 6);
    int lane = threadIdx.x & 63;
    int sub = lane / L;        // edge slot within the round
    int off = lane % L;        // 8-half chunk index within the row
    const _Float16* gbase = hin + off * 8;
    float acc[8];
    #pragma unroll
    for (int u = 0; u < 8; u++) acc[u] = 0.f;
    int deg = cnt[node];
    float dvd = rsqrtf((float)(deg + 1));
    int c = deg < CAP ? deg : CAP;
    int beg = node * CAP, end = beg + c;
    int e = beg;
    // tier 16: covers a whole typical (deg~16) node in one batch
    for (; e + 16 <= end; e += 16) {
        int s[B16]; float w[B16]; f16x8 r[B16];
        #pragma unroll
        for (int j = 0; j < B16; j++) s[j] = csr_src[e + j * G + sub];
        #pragma unroll
        for (int j = 0; j < B16; j++) r[j] = *(const f16x8*)(gbase + (size_t)s[j] * K);
        #pragma unroll
        for (int j = 0; j < B16; j++) w[j] = rsqrtf((float)(cnt[s[j]] + 1)) * dvd;
        #pragma unroll
        for (int j = 0; j < B16; j++)
            #pragma unroll
            for (int u = 0; u < 8; u++) acc[u] = fmaf(w[j], (float)r[j][u], acc[u]);
    }
    // predicated 8-edge rounds (<=2): idle lanes get weight 0 on a safe (self) row
    for (; e < end; e += 8) {
        int s[B8]; float w[B8]; f16x8 r[B8];
        #pragma unroll
        for (int j = 0; j < B8; j++) {
            int idx = e + j * G + sub;
            s[j] = (idx < end) ? csr_src[idx] : node;
        }
        #pragma unroll
        for (int j = 0; j < B8; j++)
            r[j] = *(const f16x8*)(gbase + (size_t)s[j] * K);
        #pragma unroll
        for (int j = 0; j < B8; j++) {
            int idx = e + j * G + sub;
            w[j] = (idx < end) ? rsqrtf((float)(cnt[s[j]] + 1)) * dvd : 0.f;
        }
        #pragma unroll
        for (int j = 0; j < B8; j++)
            #pragma unroll
            for (int u = 0; u < 8; u++) acc[u] = fmaf(w[j], (float)r[j][u], acc[u]);
    }
    // self loop: weight 1/(deg+1), counted once (only sub==0 lanes add it)
    {
        float sws = (sub == 0) ? dvd * dvd : 0.f;
        f16x8 rs = *(const f16x8*)(gbase + (size_t)node * K);
        #pragma unroll
        for (int u = 0; u < 8; u++) acc[u] = fmaf(sws, (float)rs[u], acc[u]);
    }
    // butterfly reduce across edge slots (partners share 'off' since L | mask)
    #pragma unroll
    for (int u = 0; u < 8; u++) {
        float v = acc[u];
        #pragma unroll
        for (int m = L; m < 64; m <<= 1) v += __shfl_xor(v, m, 64);
        acc[u] = v;
    }
    if (sub == 0) {
        f16x8 o;
        #pragma unroll
        for (int u = 0; u < 8; u++) o[u] = (_Float16)acc[u];
        *(f16x8*)(tout + (size_t)node * K + off * 8) = o;
    }
}

// ---------------- fp16 MFMA GEMM: C[M x 256] = relu(A * W^T + bias) ----------------
// BM=64 x BN=64, BK=64, 4 waves, wave tile 32x32 (2x2 of 16x16x32), 8 MFMA/wave/step.
// vs r1 (BK=32, measured-best): half the barriers; vs r7 (chunk-major, regressed):
// staging stays COALESCED. LDS row-major [64 rows][64 halves] with XOR swizzle
// slot = chunk ^ (row&7), realized via pre-swizzled GLOBAL source (m173 pattern):
// thread t stages (row=t>>3, slot=t&7) at linear dest t*16B; source chunk
// (t&7)^(row&7) -- the 8 threads of a row read one contiguous 128B segment (permuted
// within it). MFMA b128 reads hit slot (kk*4+q)^(lm&7): uniform over 8 bank-groups,
// conflict-free. 16 KB LDS + launch_bounds(256,8) -> 8 blocks/CU.
// Epilogue (non-pool): C tile bounced through lsA -> 2 coalesced dwordx4 stores/thread
// (was 16 scalar 2B stores/lane).
// FUSE_POOL=true (layer 3): epilogue run-sums per graph (batch sorted) -> atomicAdd.
template<int K, bool FUSE_POOL>
__global__ __launch_bounds__(256, 8) void k_gemm(const _Float16* __restrict__ A,
        const _Float16* __restrict__ W, const float* __restrict__ bias,
        _Float16* __restrict__ Cb, const int* __restrict__ batch,
        float* __restrict__ sums) {
    __shared__ __align__(16) _Float16 lsA[64 * 64];
    __shared__ __align__(16) _Float16 lsB[64 * 64];
    int t = threadIdx.x;
    int bm = blockIdx.x * 64;
    int bn = blockIdx.y * 64;
    int lane = t & 63, wv = t >> 6;
    int wm = (wv & 1) * 32;
    int wn = (wv >> 1) * 32;
    int lm = lane & 15, q = lane >> 4;
    int r8 = t >> 3;                 // local row 0..31 (and +32 for second load)
    int cs = t & 7;                  // stored slot
    int c0 = (cs ^ (r8 & 7)) * 8;    // actual chunk staged into slot cs (pre-swizzle)
    int ra0 = bm + r8;      if (ra0 >= NN) ra0 = NN - 1;
    int ra1 = bm + 32 + r8; if (ra1 >= NN) ra1 = NN - 1;
    int rb0 = bn + r8;
    int rb1 = bn + 32 + r8;
    const _Float16* gA0 = A + (size_t)ra0 * K + c0;
    const _Float16* gA1 = A + (size_t)ra1 * K + c0;   // (32+r8)&7 == r8&7: same swizzle
    const _Float16* gW0 = W + (size_t)rb0 * K + c0;
    const _Float16* gW1 = W + (size_t)rb1 * K + c0;
    _Float16* dA = lsA + t * 8;      // row r8 slot cs == byte t*16 (lane-contiguous)
    _Float16* dW = lsB + t * 8;

    f32x4 acc[2][2];
    #pragma unroll
    for (int i = 0; i < 2; i++)
        #pragma unroll
        for (int j = 0; j < 2; j++) acc[i][j] = (f32x4){0.f, 0.f, 0.f, 0.f};

    for (int k0 = 0; k0 < K; k0 += 64) {
        __syncthreads();  // previous tile fully consumed before LDS overwrite
        gload_lds16(gA0 + k0, dA);
        gload_lds16(gA1 + k0, dA + 2048);   // rows 32..63 half of the tile
        gload_lds16(gW0 + k0, dW);
        gload_lds16(gW1 + k0, dW + 2048);
        __syncthreads();  // drains vmcnt (compiler inserts) + all lanes staged
        #pragma unroll
        for (int kk = 0; kk < 2; kk++) {
            f16x8 bf[2], af[2];
            #pragma unroll
            for (int nt = 0; nt < 2; nt++) {
                int row = wn + nt * 16 + lm;
                bf[nt] = *(const f16x8*)&lsB[row * 64 + (((kk * 4 + q) ^ (row & 7)) * 8)];
            }
            #pragma unroll
            for (int mt = 0; mt < 2; mt++) {
                int row = wm + mt * 16 + lm;
                af[mt] = *(const f16x8*)&lsA[row * 64 + (((kk * 4 + q) ^ (row & 7)) * 8)];
            }
            #pragma unroll
            for (int mt = 0; mt < 2; mt++)
                #pragma unroll
                for (int nt = 0; nt < 2; nt++)
                    acc[mt][nt] = __builtin_amdgcn_mfma_f32_16x16x32_f16(af[mt], bf[nt], acc[mt][nt], 0, 0, 0);
        }
    }
    // epilogue: C/D layout col = lane&15, row = q*4 + r
    if constexpr (!FUSE_POOL) {
        __syncthreads();   // all MFMA LDS reads done; reuse lsA for the C tile
        #pragma unroll
        for (int mt = 0; mt < 2; mt++) {
            #pragma unroll
            for (int nt = 0; nt < 2; nt++) {
                int col = wn + nt * 16 + lm;
                float bv = bias[bn + col];
                #pragma unroll
                for (int r = 0; r < 4; r++) {
                    int row = wm + mt * 16 + q * 4 + r;
                    lsA[row * 64 + col] = (_Float16)fmaxf(acc[mt][nt][r] + bv, 0.f);
                }
            }
        }
        __syncthreads();
        // coalesced store: thread t -> rows t>>3 and 32+(t>>3), 16B at col (t&7)*8
        int lr = t >> 3, lc = (t & 7) * 8;
        f16x8 v0 = *(const f16x8*)&lsA[lr * 64 + lc];
        f16x8 v1 = *(const f16x8*)&lsA[(lr + 32) * 64 + lc];
        int orow0 = bm + lr, orow1 = bm + 32 + lr;
        if (orow0 < NN) *(f16x8*)&Cb[(size_t)orow0 * 256 + bn + lc] = v0;
        if (orow1 < NN) *(f16x8*)&Cb[(size_t)orow1 * 256 + bn + lc] = v1;
    } else {
        // graph ids for this lane's 8 rows (ascending; reused across nt)
        int gid[8];
        #pragma unroll
        for (int mt = 0; mt < 2; mt++)
            #pragma unroll
            for (int r = 0; r < 4; r++) {
                int row = bm + wm + mt * 16 + q * 4 + r;
                gid[mt * 4 + r] = (row < NN) ? batch[row] : -1;
            }
        #pragma unroll
        for (int nt = 0; nt < 2; nt++) {
            int col = bn + wn + nt * 16 + lm;
            float bv = bias[col];
            float runsum = 0.f;
            int curg = -1;
            #pragma unroll
            for (int mt = 0; mt < 2; mt++) {
                #pragma unroll
                for (int r = 0; r < 4; r++) {
                    int g = gid[mt * 4 + r];
                    if (g >= 0) {
                        float v = fmaxf(acc[mt][nt][r] + bv, 0.f);
                        if (g != curg) {
                            if (curg >= 0) atomicAdd(&sums[curg * DH + col], runsum);
                            curg = g;
                            runsum = 0.f;
                        }
                        runsum += v;
                    }
                }
            }
            if (curg >= 0) atomicAdd(&sums[curg * DH + col], runsum);
        }
    }
}

// ---------------- FC: out[G x 60] = (sums[g]/cnt) @ Wfc[60 x 256]^T + bfc ----------------
__global__ __launch_bounds__(64) void k_fc(const float* __restrict__ sums,
        const int* __restrict__ batch, const float* __restrict__ Wfc,
        const float* __restrict__ bfc, float* __restrict__ out) {
    __shared__ float p[DH];
    int g = blockIdx.x;
    int t = threadIdx.x;
    int lo = 0, hi = NN;
    while (lo < hi) { int mid = (lo + hi) >> 1; if (batch[mid] < g) lo = mid + 1; else hi = mid; }
    int start = lo;
    hi = NN;
    while (lo < hi) { int mid = (lo + hi) >> 1; if (batch[mid] < g + 1) lo = mid + 1; else hi = mid; }
    int cnt = lo - start;
    float inv = (cnt > 0) ? 1.f / (float)cnt : 0.f;
    for (int i = t; i < DH; i += 64) p[i] = sums[g * DH + i] * inv;
    __syncthreads();
    if (t < NC) {
        float a = bfc[t];
        for (int k = 0; k < DH; k++) a = fmaf(p[k], Wfc[t * DH + k], a);
        out[g * NC + t] = a;
    }
}

extern "C" void kernel_launch(void* const* d_in, const int* in_sizes, int n_in,
                              void* d_out, int out_size, void* d_ws, size_t ws_size,
                              hipStream_t stream) {
    const float* x     = (const float*)d_in[0];
    const int*   ei    = (const int*)d_in[1];
    const int*   batch = (const int*)d_in[2];
    const float* W1 = (const float*)d_in[3];
    const float* b1 = (const float*)d_in[4];
    const float* W2 = (const float*)d_in[5];
    const float* b2 = (const float*)d_in[6];
    const float* W3 = (const float*)d_in[7];
    const float* b3 = (const float*)d_in[8];
    const float* Wfc = (const float*)d_in[9];
    const float* bfc = (const float*)d_in[10];
    float* out = (float*)d_out;

    char* wp = (char*)d_ws;
    auto alloc = [&](size_t bytes) {
        char* q = wp;
        wp += (bytes + 511) & ~(size_t)511;
        return (void*)q;
    };
    int*   cursor  = (int*)alloc((size_t)NN * 4);               // true in-degree after pre
    int*   csr_src = (int*)alloc((size_t)NN * CAP * 4);         // bucket CSR
    float* sums    = (float*)alloc((size_t)NG * DH * 4);        // zeroed inside k_pre
    _Float16* xh   = (_Float16*)alloc((size_t)NN * DIN * 2);
    _Float16* tb   = (_Float16*)alloc((size_t)NN * DH * 2);
    _Float16* hA   = (_Float16*)alloc((size_t)NN * DH * 2);
    _Float16* hB   = (_Float16*)alloc((size_t)NN * DH * 2);
    _Float16* w1h = (_Float16*)alloc((size_t)DH * DIN * 2);
    _Float16* w2h = (_Float16*)alloc((size_t)DH * DH * 2);
    _Float16* w3h = (_Float16*)alloc((size_t)DH * DH * 2);

    // only cursor must be zero before pre's atomics (120 KB)
    hipMemsetAsync(cursor, 0, (size_t)NN * 4, stream);

    k_pre<<<(P1MAX + 255) / 256, 256, 0, stream>>>(ei, cursor, csr_src, x, xh,
                                                   W1, W2, W3, w1h, w2h, w3h, sums);

    dim3 gg((NN + 63) / 64, 4);
    // h_l = relu((A.h_{l-1}) W^T + b)  [linearity reorder]
    k_agg<128><<<NN / 4, 256, 0, stream>>>(xh, tb, cursor, csr_src);
    k_gemm<128, false><<<gg, 256, 0, stream>>>(tb, w1h, b1, hA, nullptr, nullptr);
    k_agg<256><<<NN / 4, 256, 0, stream>>>(hA, tb, cursor, csr_src);
    k_gemm<256, false><<<gg, 256, 0, stream>>>(tb, w2h, b2, hB, nullptr, nullptr);
    k_agg<256><<<NN / 4, 256, 0, stream>>>(hB, tb, cursor, csr_src);
    k_gemm<256, true><<<gg, 256, 0, stream>>>(tb, w3h, b3, nullptr, batch, sums);  // + pool

    k_fc<<<NG, 64, 0, stream>>>(sums, batch, Wfc, bfc, out);
}